// Round 4
// baseline (183.141 us; speedup 1.0000x reference)
//
#include <hip/hip_runtime.h>
#include <hip/hip_bf16.h>
#include <math.h>

#define NEG_SLOPE 0.2f
#define BSH    7          // log2(nodes per bucket)
#define BNODES 128        // nodes per bucket
#define CAP    2560       // max edges per bucket in LDS (mean 2048, 11 sigma)
#define MAXB   1024       // bucket count (covers up to 131072 nodes)
#define NCHUNK 256        // partition chunks
#define CEMAX  6272       // max edges per chunk staged in LDS (CE = 6250)
#define SMEMB  39424      // fused-kernel LDS bytes: part path 39424 > linear 16384

typedef __attribute__((ext_vector_type(8))) short bf16x8;
typedef __attribute__((ext_vector_type(4))) float f32x4;

__device__ __forceinline__ float leaky(float v) { return v >= 0.0f ? v : NEG_SLOPE * v; }
__device__ __forceinline__ int clampi(int v, int lo, int hi) {
    return v < lo ? lo : (v > hi ? hi : v);
}
// decode packed bf16 pair (low word / high word of a uint)
__device__ __forceinline__ float bflo(unsigned u) { return __uint_as_float(u << 16); }
__device__ __forceinline__ float bfhi(unsigned u) { return __uint_as_float(u & 0xFFFF0000u); }
// fp32 -> bf16 round-to-nearest-even
__device__ __forceinline__ unsigned short f2bf(float f) {
    unsigned u = __float_as_uint(f);
    return (unsigned short)((u + 0x7FFFu + ((u >> 16) & 1u)) >> 16);
}
__device__ __forceinline__ bf16x8 pack8(float4 a, float4 b) {
    bf16x8 r;
    r[0] = (short)f2bf(a.x); r[1] = (short)f2bf(a.y);
    r[2] = (short)f2bf(a.z); r[3] = (short)f2bf(a.w);
    r[4] = (short)f2bf(b.x); r[5] = (short)f2bf(b.y);
    r[6] = (short)f2bf(b.z); r[7] = (short)f2bf(b.w);
    return r;
}
// bijective XCD-chunked swizzle (m204): consecutive output ids share an XCD
__device__ __forceinline__ int xcd_swz(int orig, int nwg) {
    int xcd = orig & 7;
    int i   = orig >> 3;
    int qq  = nwg >> 3, rr = nwg & 7;
    int base = (xcd < rr) ? xcd * (qq + 1) : rr * (qq + 1) + (xcd - rr) * qq;
    return base + i;
}

// K1 (fused): blocks [0, nb_lin) = MFMA linear+epilogue; blocks
// [nb_lin, nb_lin+NCHUNK) = chunk-local edge binning. Data-independent halves
// run concurrently. (unchanged from round 3)
__global__ __launch_bounds__(512) void k_fused(
    const float* __restrict__ x, const float* __restrict__ W,
    const float* __restrict__ att_src, const float* __restrict__ att_dst,
    __hip_bfloat16* __restrict__ h, float* __restrict__ a_s,
    float* __restrict__ a_d, const int* __restrict__ ei,
    unsigned* __restrict__ binned, int* __restrict__ offc,
    int N, int E, int CE, int nb_lin)
{
    __shared__ int4 smem4[SMEMB / 16];
    const int tid = threadIdx.x;

    if ((int)blockIdx.x < nb_lin) {
        short* wlds = (short*)smem4;      // 16 frag-sets x 64 lanes x 8 bf16

        for (int idx = tid; idx < 1024; idx += 512) {
            int f = idx >> 6, L = idx & 63;
            int t = f >> 2, k0i = f & 3;
            int kbase = k0i * 32 + (L >> 4) * 8;
            int c = t * 16 + (L & 15);
            unsigned short v[8];
#pragma unroll
            for (int j = 0; j < 8; ++j) v[j] = f2bf(W[(kbase + j) * 64 + c]);
            uint4 p;
            p.x = (unsigned)v[0] | ((unsigned)v[1] << 16);
            p.y = (unsigned)v[2] | ((unsigned)v[3] << 16);
            p.z = (unsigned)v[4] | ((unsigned)v[5] << 16);
            p.w = (unsigned)v[6] | ((unsigned)v[7] << 16);
            ((uint4*)wlds)[idx] = p;
        }
        __syncthreads();

        const int lane = tid & 63;
        const int w    = tid >> 6;
        const int base = blockIdx.x * 128 + w * 16;
        const int m    = lane & 15;
        const int quad = lane >> 4;

        int rowc = min(base + m, N - 1);
        const float4* xr = (const float4*)x + (size_t)rowc * 32;

        bf16x8 afrag[4];
#pragma unroll
        for (int k0i = 0; k0i < 4; ++k0i) {
            float4 f0 = xr[k0i * 8 + quad * 2 + 0];
            float4 f1 = xr[k0i * 8 + quad * 2 + 1];
            afrag[k0i] = pack8(f0, f1);
        }

        f32x4 acc[4];
#pragma unroll
        for (int t = 0; t < 4; ++t) acc[t] = (f32x4){0.f, 0.f, 0.f, 0.f};

        const bf16x8* wf = (const bf16x8*)wlds;
#pragma unroll
        for (int t = 0; t < 4; ++t) {
#pragma unroll
            for (int k0i = 0; k0i < 4; ++k0i) {
                bf16x8 bfr = wf[(t * 4 + k0i) * 64 + lane];
                acc[t] = __builtin_amdgcn_mfma_f32_16x16x32_bf16(afrag[k0i], bfr, acc[t], 0, 0, 0);
            }
        }

        float ps[4] = {0.f, 0.f, 0.f, 0.f};
        float pd[4] = {0.f, 0.f, 0.f, 0.f};
#pragma unroll
        for (int t = 0; t < 4; ++t) {
            float as_c = att_src[t * 16 + m];
            float ad_c = att_dst[t * 16 + m];
#pragma unroll
            for (int q = 0; q < 4; ++q) {
                ps[q] = fmaf(acc[t][q], as_c, ps[q]);
                pd[q] = fmaf(acc[t][q], ad_c, pd[q]);
            }
        }
#pragma unroll
        for (int t = 0; t < 4; ++t) {
#pragma unroll
            for (int q = 0; q < 4; ++q) {
                int n = base + quad * 4 + q;
                if (n < N) h[(size_t)n * 64 + t * 16 + m] = __float2bfloat16(acc[t][q]);
            }
        }
#pragma unroll
        for (int q = 0; q < 4; ++q) {
            ps[q] += __shfl_xor(ps[q], 1, 64);
            ps[q] += __shfl_xor(ps[q], 2, 64);
            ps[q] += __shfl_xor(ps[q], 4, 64);
            ps[q] += __shfl_xor(ps[q], 8, 64);
            pd[q] += __shfl_xor(pd[q], 1, 64);
            pd[q] += __shfl_xor(pd[q], 2, 64);
            pd[q] += __shfl_xor(pd[q], 4, 64);
            pd[q] += __shfl_xor(pd[q], 8, 64);
        }
        if (m == 0) {
#pragma unroll
            for (int q = 0; q < 4; ++q) {
                int n = base + quad * 4 + q;
                if (n < N) { a_s[n] = ps[q]; a_d[n] = pd[q]; }
            }
        }
    } else {
        int* hist = (int*)smem4;              // 1024
        int* off  = hist + MAXB;              // 1024
        int* cur  = off + MAXB;               // 1024
        int* s    = cur + MAXB;               // 512
        unsigned* stage = (unsigned*)(s + 512);  // CEMAX

        const int c  = (int)blockIdx.x - nb_lin;
        const int e0 = c * CE;
        const int e1 = min(E, e0 + CE);
        const int ne = e1 - e0;

        for (int i = tid; i < MAXB; i += 512) hist[i] = 0;
        __syncthreads();
        for (int e = e0 + tid; e < e1; e += 512) {
            int dst = clampi(ei[E + e], 0, N - 1);
            atomicAdd(&hist[dst >> BSH], 1);
        }
        __syncthreads();
        int a0 = hist[2 * tid], a1 = hist[2 * tid + 1];
        int psum = a0 + a1;
        s[tid] = psum;
        __syncthreads();
        for (int d = 1; d < 512; d <<= 1) {
            int v = (tid >= d) ? s[tid - d] : 0;
            __syncthreads();
            s[tid] += v;
            __syncthreads();
        }
        int excl = s[tid] - psum;
        off[2 * tid]     = excl;
        off[2 * tid + 1] = excl + a0;
        cur[2 * tid]     = excl;
        cur[2 * tid + 1] = excl + a0;
        __syncthreads();
        for (int e = e0 + tid; e < e1; e += 512) {
            int src = clampi(ei[e],     0, N - 1);
            int dst = clampi(ei[E + e], 0, N - 1);
            int pos = atomicAdd(&cur[dst >> BSH], 1);
            stage[clampi(pos, 0, CEMAX - 1)] =
                ((unsigned)(dst & (BNODES - 1)) << 17) | (unsigned)src;
        }
        __syncthreads();
        for (int i = tid; i < ne; i += 512) binned[e0 + i] = stage[i];
        int* oc = offc + (size_t)c * (MAXB + 1);
        for (int i = tid; i < MAXB; i += 512) oc[i] = off[i];
        if (tid == 0) oc[MAXB] = ne;
    }
}

// K2: one block (512 threads, 8 waves) per 128-node bucket.
// Round-4 changes: (1) XCD-chunked block->bucket swizzle for offc/binned L2
// sharing between neighbor buckets; (2) degree-sort the 128 nodes (bitonic,
// in LDS) and snake-assign rank groups to waves -> wave-pass max(deg) ~= mean
// (removes ~1.6x exec-mask waste); (3) depth-4 software pipeline, unroll-4,
// in the edge gather loop (named buffers only, no runtime-indexed arrays).
#define CONS(Uv, wv) \
    acc0 = fmaf(wv, bflo(Uv.x), acc0); \
    acc1 = fmaf(wv, bfhi(Uv.x), acc1); \
    acc2 = fmaf(wv, bflo(Uv.y), acc2); \
    acc3 = fmaf(wv, bfhi(Uv.y), acc3); \
    acc4 = fmaf(wv, bflo(Uv.z), acc4); \
    acc5 = fmaf(wv, bfhi(Uv.z), acc5); \
    acc6 = fmaf(wv, bflo(Uv.w), acc6); \
    acc7 = fmaf(wv, bfhi(Uv.w), acc7);
#define LOADE(idx, Uv, wv) { uint2 _ee = ew[s0 + (idx)]; \
    wv = __uint_as_float(_ee.y); Uv = h4[(size_t)_ee.x * 8 + q]; }

__global__ __launch_bounds__(512, 8) void k_agg(
    const unsigned* __restrict__ binned, const int* __restrict__ offc,
    const float* __restrict__ a_s, const float* __restrict__ a_d,
    const __hip_bfloat16* __restrict__ hm, const float* __restrict__ bias,
    float* __restrict__ out, int N, int CE)
{
    __shared__ int   cnt[BNODES];
    __shared__ int   st[BNODES];
    __shared__ int   cur[BNODES];
    __shared__ float lsum[BNODES];
    __shared__ float wsl[BNODES];
    __shared__ float adl[BNODES];
    __shared__ unsigned skey[BNODES];   // (deg<<7)|ln, sorted ascending
    __shared__ int   runScan[NCHUNK + 1];
    __shared__ int   gbase[NCHUNK];
    __shared__ int   sc[NCHUNK];
    __shared__ unsigned eraw[CAP];
    __shared__ uint2 ew[CAP];          // .x = src node, .y = f32 bits of w

    const int tid   = threadIdx.x;
    const int b     = xcd_swz((int)blockIdx.x, (int)gridDim.x);
    const int nbase = b << BSH;

    if (tid < BNODES) {
        cnt[tid] = 0;
        int n = nbase + tid;
        float as = 0.f, ad = 0.f;
        if (n < N) { as = a_s[n]; ad = a_d[n]; }
        adl[tid] = ad;
        float v = (n < N) ? __expf(leaky(as + ad)) : 0.f;
        wsl[tid]  = v;
        lsum[tid] = v;
    }
    int rc = 0;
    if (tid < NCHUNK) {
        const int* oc = offc + (size_t)tid * (MAXB + 1);
        int o0 = clampi(oc[b],     0, CE);
        int o1 = clampi(oc[b + 1], o0, CE);
        rc = o1 - o0;
        gbase[tid] = tid * CE + o0;
        sc[tid] = rc;
    }
    __syncthreads();
    for (int d = 1; d < NCHUNK; d <<= 1) {      // inclusive scan of run lengths
        int v = (tid < NCHUNK && tid >= d) ? sc[tid - d] : 0;
        __syncthreads();
        if (tid < NCHUNK) sc[tid] += v;
        __syncthreads();
    }
    if (tid < NCHUNK) runScan[tid] = sc[tid] - rc;   // exclusive
    if (tid == NCHUNK - 1) runScan[NCHUNK] = sc[NCHUNK - 1];
    __syncthreads();
    int n_e = runScan[NCHUNK];
    if (n_e > CAP) n_e = CAP;          // statistically never

    // coalesced element-parallel copy: global binned -> LDS eraw
    for (int i = tid; i < n_e; i += 512) {
        int c = 0;
#pragma unroll
        for (int stp = NCHUNK >> 1; stp >= 1; stp >>= 1)
            if (runScan[c + stp] <= i) c += stp;
        eraw[i] = binned[(size_t)gbase[c] + (i - runScan[c])];
    }
    __syncthreads();
    // per-node histogram (LDS only)
    for (int i = tid; i < n_e; i += 512)
        atomicAdd(&cnt[(eraw[i] >> 17) & (BNODES - 1)], 1);
    __syncthreads();
    if (tid < BNODES) st[tid] = cnt[tid];
    __syncthreads();
    for (int d = 1; d < BNODES; d <<= 1) {      // Hillis-Steele inclusive
        int v = (tid < BNODES && tid >= d) ? st[tid - d] : 0;
        __syncthreads();
        if (tid < BNODES) st[tid] += v;
        __syncthreads();
    }
    if (tid < BNODES) { st[tid] -= cnt[tid]; cur[tid] = st[tid]; }  // exclusive
    __syncthreads();
    // scatter + fused attention weight + denominator (LDS -> LDS)
    for (int i = tid; i < n_e; i += 512) {
        unsigned pk = eraw[i];
        int ld  = (int)(pk >> 17) & (BNODES - 1);
        int src = (int)(pk & 0x1FFFFu);
        float wv = __expf(leaky(a_s[src] + adl[ld]));
        int pos = atomicAdd(&cur[ld], 1);
        if (pos < CAP) ew[pos] = make_uint2((unsigned)src, __float_as_uint(wv));
        atomicAdd(&lsum[ld], wv);
    }
    // degree sort: skey init then bitonic ascending (first loop barrier
    // also covers the scatter pass above)
    if (tid < BNODES) skey[tid] = ((unsigned)cnt[tid] << 7) | (unsigned)tid;
    for (int k = 2; k <= BNODES; k <<= 1) {
        for (int jj = k >> 1; jj > 0; jj >>= 1) {
            __syncthreads();
            if (tid < BNODES) {
                int ixj = tid ^ jj;
                if (ixj > tid) {
                    unsigned va = skey[tid], vb = skey[ixj];
                    if ((((tid & k) == 0)) == (va > vb)) {
                        skey[tid] = vb; skey[ixj] = va;
                    }
                }
            }
        }
    }
    __syncthreads();

    // Phase B: lane = (node-slot p = lane>>3, octet q = lane&7); snake order.
    const int lane = tid & 63;
    const int w    = tid >> 6;       // wave 0..7
    const int q    = lane & 7;       // feature octet: features 8q..8q+7
    const int p    = lane >> 3;      // node slot 0..7
    const uint4*  h4 = (const uint4*)hm;
    const float4* b4 = (const float4*)bias;
    const float4 bb0 = b4[2 * q];
    const float4 bb1 = b4[2 * q + 1];

#pragma unroll 1
    for (int pass = 0; pass < 2; ++pass) {
        int grp = (pass == 0) ? w : (15 - w);      // snake: balance wave totals
        int ln  = (int)(skey[grp * 8 + p] & 127u); // 8 similar-degree nodes/wave
        int n   = nbase + ln;
        if (n >= N) continue;
        int s0  = st[ln];
        if (s0 > CAP) s0 = CAP;
        int deg = cnt[ln];
        if (deg > CAP - s0) deg = CAP - s0;

        // self-loop contribution
        float wself = wsl[ln];
        uint4 U = h4[(size_t)n * 8 + q];
        float acc0 = wself * bflo(U.x), acc1 = wself * bfhi(U.x);
        float acc2 = wself * bflo(U.y), acc3 = wself * bfhi(U.y);
        float acc4 = wself * bflo(U.z), acc5 = wself * bfhi(U.z);
        float acc6 = wself * bflo(U.w), acc7 = wself * bfhi(U.w);

        // depth-4 pipeline, unroll-4
        uint4 UA = make_uint4(0,0,0,0), UB = UA, UC = UA, UD = UA;
        float wa = 0.f, wb = 0.f, wcv = 0.f, wd = 0.f;
        if (deg > 0) LOADE(0, UA, wa);
        if (deg > 1) LOADE(1, UB, wb);
        if (deg > 2) LOADE(2, UC, wcv);
        if (deg > 3) LOADE(3, UD, wd);
        int j = 0;
        for (; j + 7 < deg; j += 4) {
            CONS(UA, wa); LOADE(j + 4, UA, wa);
            CONS(UB, wb); LOADE(j + 5, UB, wb);
            CONS(UC, wcv); LOADE(j + 6, UC, wcv);
            CONS(UD, wd); LOADE(j + 7, UD, wd);
        }
        if (j     < deg) { CONS(UA, wa); }
        if (j + 1 < deg) { CONS(UB, wb); }
        if (j + 2 < deg) { CONS(UC, wcv); }
        if (j + 3 < deg) { CONS(UD, wd); }
        for (int t2 = j + 4; t2 < deg; ++t2) {     // <=3 serial tail edges
            uint2 e2 = ew[s0 + t2];
            float wv = __uint_as_float(e2.y);
            uint4 U2 = h4[(size_t)e2.x * 8 + q];
            CONS(U2, wv);
        }

        float inv = 1.0f / lsum[ln];
        float4 o0, o1;
        o0.x = bb0.x + acc0 * inv;
        o0.y = bb0.y + acc1 * inv;
        o0.z = bb0.z + acc2 * inv;
        o0.w = bb0.w + acc3 * inv;
        o1.x = bb1.x + acc4 * inv;
        o1.y = bb1.y + acc5 * inv;
        o1.z = bb1.z + acc6 * inv;
        o1.w = bb1.w + acc7 * inv;
        float4* o4 = (float4*)out;
        o4[(size_t)n * 16 + 2 * q + 0] = o0;
        o4[(size_t)n * 16 + 2 * q + 1] = o1;
    }
}

extern "C" void kernel_launch(void* const* d_in, const int* in_sizes, int n_in,
                              void* d_out, int out_size, void* d_ws, size_t ws_size,
                              hipStream_t stream)
{
    const float* x       = (const float*)d_in[0];
    const int*   ei      = (const int*)d_in[1];      // int32 per harness contract
    const float* W       = (const float*)d_in[2];
    const float* att_src = (const float*)d_in[3];
    const float* att_dst = (const float*)d_in[4];
    const float* bias    = (const float*)d_in[5];
    float*       out     = (float*)d_out;

    const int N = in_sizes[0] / 128;   // 100000
    const int E = in_sizes[1] / 2;     // 1600000

    __hip_bfloat16* h      = (__hip_bfloat16*)d_ws;
    float*          a_s    = (float*)(h + (size_t)N * 64);
    float*          a_d    = a_s + N;
    int*            offc   = (int*)(a_d + N);                 // 263424 ints
    unsigned*       binned = (unsigned*)(offc + NCHUNK * (MAXB + 1));

    const int CE = (E + NCHUNK - 1) / NCHUNK;   // 6250 edges per chunk (<= CEMAX)
    const int NB = (N + BNODES - 1) >> BSH;     // 782 agg buckets
    const int nb_lin = (N + 127) / 128;         // 782 linear blocks

    k_fused<<<nb_lin + NCHUNK, 512, 0, stream>>>(x, W, att_src, att_dst,
                                                 h, a_s, a_d, ei, binned, offc,
                                                 N, E, CE, nb_lin);
    k_agg  <<<NB,              512, 0, stream>>>(binned, offc, a_s, a_d, h,
                                                 bias, out, N, CE);
}

// Round 5
// 166.729 us; speedup vs baseline: 1.0984x; 1.0984x over previous
//
#include <hip/hip_runtime.h>
#include <hip/hip_bf16.h>
#include <math.h>

#define NEG_SLOPE 0.2f
#define BSH    7          // log2(nodes per bucket)
#define BNODES 128        // nodes per bucket
#define CAP    2560       // max edges per bucket in LDS (mean 2048, 11 sigma)
#define MAXB   1024       // bucket count (covers up to 131072 nodes)
#define NCHUNK 256        // partition chunks
#define CEMAX  6272       // max edges per chunk staged in LDS (CE = 6250)
#define SMEMB  39424      // fused-kernel LDS bytes: part path 39424 > linear 16384

typedef __attribute__((ext_vector_type(8))) short bf16x8;
typedef __attribute__((ext_vector_type(4))) float f32x4;

__device__ __forceinline__ float leaky(float v) { return v >= 0.0f ? v : NEG_SLOPE * v; }
__device__ __forceinline__ int clampi(int v, int lo, int hi) {
    return v < lo ? lo : (v > hi ? hi : v);
}
// decode packed bf16 pair (low word / high word of a uint)
__device__ __forceinline__ float bflo(unsigned u) { return __uint_as_float(u << 16); }
__device__ __forceinline__ float bfhi(unsigned u) { return __uint_as_float(u & 0xFFFF0000u); }
// fp32 -> bf16 round-to-nearest-even
__device__ __forceinline__ unsigned short f2bf(float f) {
    unsigned u = __float_as_uint(f);
    return (unsigned short)((u + 0x7FFFu + ((u >> 16) & 1u)) >> 16);
}
__device__ __forceinline__ bf16x8 pack8(float4 a, float4 b) {
    bf16x8 r;
    r[0] = (short)f2bf(a.x); r[1] = (short)f2bf(a.y);
    r[2] = (short)f2bf(a.z); r[3] = (short)f2bf(a.w);
    r[4] = (short)f2bf(b.x); r[5] = (short)f2bf(b.y);
    r[6] = (short)f2bf(b.z); r[7] = (short)f2bf(b.w);
    return r;
}

// K1 (fused): blocks [0, nb_lin) = MFMA linear+epilogue; blocks
// [nb_lin, nb_lin+NCHUNK) = chunk-local edge binning. Data-independent halves
// run concurrently. (unchanged from round 3)
__global__ __launch_bounds__(512) void k_fused(
    const float* __restrict__ x, const float* __restrict__ W,
    const float* __restrict__ att_src, const float* __restrict__ att_dst,
    __hip_bfloat16* __restrict__ h, float* __restrict__ a_s,
    float* __restrict__ a_d, const int* __restrict__ ei,
    unsigned* __restrict__ binned, int* __restrict__ offc,
    int N, int E, int CE, int nb_lin)
{
    __shared__ int4 smem4[SMEMB / 16];
    const int tid = threadIdx.x;

    if ((int)blockIdx.x < nb_lin) {
        short* wlds = (short*)smem4;      // 16 frag-sets x 64 lanes x 8 bf16

        for (int idx = tid; idx < 1024; idx += 512) {
            int f = idx >> 6, L = idx & 63;
            int t = f >> 2, k0i = f & 3;
            int kbase = k0i * 32 + (L >> 4) * 8;
            int c = t * 16 + (L & 15);
            unsigned short v[8];
#pragma unroll
            for (int j = 0; j < 8; ++j) v[j] = f2bf(W[(kbase + j) * 64 + c]);
            uint4 p;
            p.x = (unsigned)v[0] | ((unsigned)v[1] << 16);
            p.y = (unsigned)v[2] | ((unsigned)v[3] << 16);
            p.z = (unsigned)v[4] | ((unsigned)v[5] << 16);
            p.w = (unsigned)v[6] | ((unsigned)v[7] << 16);
            ((uint4*)wlds)[idx] = p;
        }
        __syncthreads();

        const int lane = tid & 63;
        const int w    = tid >> 6;
        const int base = blockIdx.x * 128 + w * 16;
        const int m    = lane & 15;
        const int quad = lane >> 4;

        int rowc = min(base + m, N - 1);
        const float4* xr = (const float4*)x + (size_t)rowc * 32;

        bf16x8 afrag[4];
#pragma unroll
        for (int k0i = 0; k0i < 4; ++k0i) {
            float4 f0 = xr[k0i * 8 + quad * 2 + 0];
            float4 f1 = xr[k0i * 8 + quad * 2 + 1];
            afrag[k0i] = pack8(f0, f1);
        }

        f32x4 acc[4];
#pragma unroll
        for (int t = 0; t < 4; ++t) acc[t] = (f32x4){0.f, 0.f, 0.f, 0.f};

        const bf16x8* wf = (const bf16x8*)wlds;
#pragma unroll
        for (int t = 0; t < 4; ++t) {
#pragma unroll
            for (int k0i = 0; k0i < 4; ++k0i) {
                bf16x8 bfr = wf[(t * 4 + k0i) * 64 + lane];
                acc[t] = __builtin_amdgcn_mfma_f32_16x16x32_bf16(afrag[k0i], bfr, acc[t], 0, 0, 0);
            }
        }

        float ps[4] = {0.f, 0.f, 0.f, 0.f};
        float pd[4] = {0.f, 0.f, 0.f, 0.f};
#pragma unroll
        for (int t = 0; t < 4; ++t) {
            float as_c = att_src[t * 16 + m];
            float ad_c = att_dst[t * 16 + m];
#pragma unroll
            for (int q = 0; q < 4; ++q) {
                ps[q] = fmaf(acc[t][q], as_c, ps[q]);
                pd[q] = fmaf(acc[t][q], ad_c, pd[q]);
            }
        }
#pragma unroll
        for (int t = 0; t < 4; ++t) {
#pragma unroll
            for (int q = 0; q < 4; ++q) {
                int n = base + quad * 4 + q;
                if (n < N) h[(size_t)n * 64 + t * 16 + m] = __float2bfloat16(acc[t][q]);
            }
        }
#pragma unroll
        for (int q = 0; q < 4; ++q) {
            ps[q] += __shfl_xor(ps[q], 1, 64);
            ps[q] += __shfl_xor(ps[q], 2, 64);
            ps[q] += __shfl_xor(ps[q], 4, 64);
            ps[q] += __shfl_xor(ps[q], 8, 64);
            pd[q] += __shfl_xor(pd[q], 1, 64);
            pd[q] += __shfl_xor(pd[q], 2, 64);
            pd[q] += __shfl_xor(pd[q], 4, 64);
            pd[q] += __shfl_xor(pd[q], 8, 64);
        }
        if (m == 0) {
#pragma unroll
            for (int q = 0; q < 4; ++q) {
                int n = base + quad * 4 + q;
                if (n < N) { a_s[n] = ps[q]; a_d[n] = pd[q]; }
            }
        }
    } else {
        int* hist = (int*)smem4;              // 1024
        int* off  = hist + MAXB;              // 1024
        int* cur  = off + MAXB;               // 1024
        int* s    = cur + MAXB;               // 512
        unsigned* stage = (unsigned*)(s + 512);  // CEMAX

        const int c  = (int)blockIdx.x - nb_lin;
        const int e0 = c * CE;
        const int e1 = min(E, e0 + CE);
        const int ne = e1 - e0;

        for (int i = tid; i < MAXB; i += 512) hist[i] = 0;
        __syncthreads();
        for (int e = e0 + tid; e < e1; e += 512) {
            int dst = clampi(ei[E + e], 0, N - 1);
            atomicAdd(&hist[dst >> BSH], 1);
        }
        __syncthreads();
        int a0 = hist[2 * tid], a1 = hist[2 * tid + 1];
        int psum = a0 + a1;
        s[tid] = psum;
        __syncthreads();
        for (int d = 1; d < 512; d <<= 1) {
            int v = (tid >= d) ? s[tid - d] : 0;
            __syncthreads();
            s[tid] += v;
            __syncthreads();
        }
        int excl = s[tid] - psum;
        off[2 * tid]     = excl;
        off[2 * tid + 1] = excl + a0;
        cur[2 * tid]     = excl;
        cur[2 * tid + 1] = excl + a0;
        __syncthreads();
        for (int e = e0 + tid; e < e1; e += 512) {
            int src = clampi(ei[e],     0, N - 1);
            int dst = clampi(ei[E + e], 0, N - 1);
            int pos = atomicAdd(&cur[dst >> BSH], 1);
            stage[clampi(pos, 0, CEMAX - 1)] =
                ((unsigned)(dst & (BNODES - 1)) << 17) | (unsigned)src;
        }
        __syncthreads();
        for (int i = tid; i < ne; i += 512) binned[e0 + i] = stage[i];
        int* oc = offc + (size_t)c * (MAXB + 1);
        for (int i = tid; i < MAXB; i += 512) oc[i] = off[i];
        if (tid == 0) oc[MAXB] = ne;
    }
}

// K2: one block (512 threads, 8 waves) per 128-node bucket.
// Round 5 = round-3 structure (no sort, no swizzle, natural node order and
// coalesced writes) + ONE change: depth-4 guard-free software pipeline in the
// edge gather loop (4 named (U,w) buffer pairs -> 4 loads in flight per lane),
// with the round-3 depth-1 pipeline as the tail path. launch_bounds(512,8)
// pins VGPR <= 64 so 4 blocks/CU occupancy is preserved.
#define CONS(Uv, wv) \
    acc0 = fmaf(wv, bflo(Uv.x), acc0); \
    acc1 = fmaf(wv, bfhi(Uv.x), acc1); \
    acc2 = fmaf(wv, bflo(Uv.y), acc2); \
    acc3 = fmaf(wv, bfhi(Uv.y), acc3); \
    acc4 = fmaf(wv, bflo(Uv.z), acc4); \
    acc5 = fmaf(wv, bfhi(Uv.z), acc5); \
    acc6 = fmaf(wv, bflo(Uv.w), acc6); \
    acc7 = fmaf(wv, bfhi(Uv.w), acc7);
#define LOADE(idx, Uv, wv) { uint2 _ee = ew[s0 + (idx)]; \
    wv = __uint_as_float(_ee.y); Uv = h4[(size_t)_ee.x * 8 + q]; }

__global__ __launch_bounds__(512, 8) void k_agg(
    const unsigned* __restrict__ binned, const int* __restrict__ offc,
    const float* __restrict__ a_s, const float* __restrict__ a_d,
    const __hip_bfloat16* __restrict__ hm, const float* __restrict__ bias,
    float* __restrict__ out, int N, int CE)
{
    __shared__ int   cnt[BNODES];
    __shared__ int   st[BNODES];
    __shared__ int   cur[BNODES];
    __shared__ float lsum[BNODES];
    __shared__ float wsl[BNODES];
    __shared__ float adl[BNODES];
    __shared__ int   runScan[NCHUNK + 1];
    __shared__ int   gbase[NCHUNK];
    __shared__ int   sc[NCHUNK];
    __shared__ unsigned eraw[CAP];
    __shared__ uint2 ew[CAP];          // .x = src node, .y = f32 bits of w

    const int tid   = threadIdx.x;
    const int b     = blockIdx.x;
    const int nbase = b << BSH;

    if (tid < BNODES) {
        cnt[tid] = 0;
        int n = nbase + tid;
        float as = 0.f, ad = 0.f;
        if (n < N) { as = a_s[n]; ad = a_d[n]; }
        adl[tid] = ad;
        float v = (n < N) ? __expf(leaky(as + ad)) : 0.f;
        wsl[tid]  = v;                 // self-loop weight
        lsum[tid] = v;                 // denominator starts with self loop
    }
    int rc = 0;
    if (tid < NCHUNK) {
        const int* oc = offc + (size_t)tid * (MAXB + 1);
        int o0 = clampi(oc[b],     0, CE);
        int o1 = clampi(oc[b + 1], o0, CE);
        rc = o1 - o0;
        gbase[tid] = tid * CE + o0;
        sc[tid] = rc;
    }
    __syncthreads();
    for (int d = 1; d < NCHUNK; d <<= 1) {      // inclusive scan of run lengths
        int v = (tid < NCHUNK && tid >= d) ? sc[tid - d] : 0;
        __syncthreads();
        if (tid < NCHUNK) sc[tid] += v;
        __syncthreads();
    }
    if (tid < NCHUNK) runScan[tid] = sc[tid] - rc;   // exclusive
    if (tid == NCHUNK - 1) runScan[NCHUNK] = sc[NCHUNK - 1];
    __syncthreads();
    int n_e = runScan[NCHUNK];
    if (n_e > CAP) n_e = CAP;          // statistically never

    // coalesced element-parallel copy: global binned -> LDS eraw
    for (int i = tid; i < n_e; i += 512) {
        int c = 0;
#pragma unroll
        for (int stp = NCHUNK >> 1; stp >= 1; stp >>= 1)
            if (runScan[c + stp] <= i) c += stp;
        eraw[i] = binned[(size_t)gbase[c] + (i - runScan[c])];
    }
    __syncthreads();
    // per-node histogram (LDS only)
    for (int i = tid; i < n_e; i += 512)
        atomicAdd(&cnt[(eraw[i] >> 17) & (BNODES - 1)], 1);
    __syncthreads();
    if (tid < BNODES) st[tid] = cnt[tid];
    __syncthreads();
    for (int d = 1; d < BNODES; d <<= 1) {      // Hillis-Steele inclusive
        int v = (tid < BNODES && tid >= d) ? st[tid - d] : 0;
        __syncthreads();
        if (tid < BNODES) st[tid] += v;
        __syncthreads();
    }
    if (tid < BNODES) { st[tid] -= cnt[tid]; cur[tid] = st[tid]; }  // exclusive
    __syncthreads();
    // scatter + fused attention weight + denominator (LDS -> LDS)
    for (int i = tid; i < n_e; i += 512) {
        unsigned pk = eraw[i];
        int ld  = (int)(pk >> 17) & (BNODES - 1);
        int src = (int)(pk & 0x1FFFFu);
        float wv = __expf(leaky(a_s[src] + adl[ld]));
        int pos = atomicAdd(&cur[ld], 1);
        if (pos < CAP) ew[pos] = make_uint2((unsigned)src, __float_as_uint(wv));
        atomicAdd(&lsum[ld], wv);
    }
    __syncthreads();

    // Phase B: lane = (node-slot p = lane>>3, octet q = lane&7)
    const int lane = tid & 63;
    const int w    = tid >> 6;       // wave 0..7
    const int q    = lane & 7;       // feature octet: features 8q..8q+7
    const int p    = lane >> 3;      // node slot 0..7
    const uint4*  h4 = (const uint4*)hm;
    const float4* b4 = (const float4*)bias;
    const float4 bb0 = b4[2 * q];
    const float4 bb1 = b4[2 * q + 1];

#pragma unroll 1
    for (int t = 0; t < 2; ++t) {
        int ln = t * 64 + w * 8 + p;
        int n  = nbase + ln;
        if (n >= N) continue;
        int deg = cnt[ln];
        int s0  = st[ln];
        if (s0 > CAP) s0 = CAP;            // defensive (never in practice)
        if (deg > CAP - s0) deg = CAP - s0;

        // self-loop contribution (each lane owns its octet exactly once)
        float wself = wsl[ln];
        uint4 U = h4[(size_t)n * 8 + q];
        float acc0 = wself * bflo(U.x), acc1 = wself * bfhi(U.x);
        float acc2 = wself * bflo(U.y), acc3 = wself * bfhi(U.y);
        float acc4 = wself * bflo(U.z), acc5 = wself * bfhi(U.z);
        float acc6 = wself * bflo(U.w), acc7 = wself * bfhi(U.w);

        int j = 0;
        if (deg >= 8) {
            // depth-4 pipeline, guard-free unroll-4 main loop
            uint4 UA, UB, UC, UD;
            float wa, wb, wcv, wd;
            LOADE(0, UA, wa);
            LOADE(1, UB, wb);
            LOADE(2, UC, wcv);
            LOADE(3, UD, wd);
            for (; j + 7 < deg; j += 4) {
                CONS(UA, wa);  LOADE(j + 4, UA, wa);
                CONS(UB, wb);  LOADE(j + 5, UB, wb);
                CONS(UC, wcv); LOADE(j + 6, UC, wcv);
                CONS(UD, wd);  LOADE(j + 7, UD, wd);
            }
            CONS(UA, wa); CONS(UB, wb); CONS(UC, wcv); CONS(UD, wd);
            j += 4;
        }
        if (j < deg) {
            // tail (deg<8, or last <=3 edges): depth-1 pipeline (round-3 form)
            uint2 et = ew[s0 + j];
            float wt = __uint_as_float(et.y);
            uint4 Ut = h4[(size_t)et.x * 8 + q];
            for (; j < deg; ++j) {
                uint4 U2 = make_uint4(0u, 0u, 0u, 0u);
                float w2 = 0.f;
                if (j + 1 < deg) {
                    uint2 e2 = ew[s0 + j + 1];
                    w2 = __uint_as_float(e2.y);
                    U2 = h4[(size_t)e2.x * 8 + q];
                }
                CONS(Ut, wt);
                Ut = U2; wt = w2;
            }
        }

        float inv = 1.0f / lsum[ln];
        float4 o0, o1;
        o0.x = bb0.x + acc0 * inv;
        o0.y = bb0.y + acc1 * inv;
        o0.z = bb0.z + acc2 * inv;
        o0.w = bb0.w + acc3 * inv;
        o1.x = bb1.x + acc4 * inv;
        o1.y = bb1.y + acc5 * inv;
        o1.z = bb1.z + acc6 * inv;
        o1.w = bb1.w + acc7 * inv;
        float4* o4 = (float4*)out;
        o4[(size_t)n * 16 + 2 * q + 0] = o0;
        o4[(size_t)n * 16 + 2 * q + 1] = o1;
    }
}

extern "C" void kernel_launch(void* const* d_in, const int* in_sizes, int n_in,
                              void* d_out, int out_size, void* d_ws, size_t ws_size,
                              hipStream_t stream)
{
    const float* x       = (const float*)d_in[0];
    const int*   ei      = (const int*)d_in[1];      // int32 per harness contract
    const float* W       = (const float*)d_in[2];
    const float* att_src = (const float*)d_in[3];
    const float* att_dst = (const float*)d_in[4];
    const float* bias    = (const float*)d_in[5];
    float*       out     = (float*)d_out;

    const int N = in_sizes[0] / 128;   // 100000
    const int E = in_sizes[1] / 2;     // 1600000

    __hip_bfloat16* h      = (__hip_bfloat16*)d_ws;
    float*          a_s    = (float*)(h + (size_t)N * 64);
    float*          a_d    = a_s + N;
    int*            offc   = (int*)(a_d + N);                 // 263424 ints
    unsigned*       binned = (unsigned*)(offc + NCHUNK * (MAXB + 1));

    const int CE = (E + NCHUNK - 1) / NCHUNK;   // 6250 edges per chunk (<= CEMAX)
    const int NB = (N + BNODES - 1) >> BSH;     // 782 agg buckets
    const int nb_lin = (N + 127) / 128;         // 782 linear blocks

    k_fused<<<nb_lin + NCHUNK, 512, 0, stream>>>(x, W, att_src, att_dst,
                                                 h, a_s, a_d, ei, binned, offc,
                                                 N, E, CE, nb_lin);
    k_agg  <<<NB,              512, 0, stream>>>(binned, offc, a_s, a_d, h,
                                                 bias, out, N, CE);
}

// Round 6
// 161.582 us; speedup vs baseline: 1.1334x; 1.0319x over previous
//
#include <hip/hip_runtime.h>
#include <hip/hip_bf16.h>
#include <math.h>

#define NEG_SLOPE 0.2f
#define BSH    7          // log2(nodes per bucket)
#define BNODES 128        // nodes per bucket
#define CAP    2560       // max edges per bucket in LDS (mean 2048, 11 sigma)
#define MAXB   1024       // bucket count (covers up to 131072 nodes)
#define NCHUNK 256        // partition chunks
#define CEMAX  6272       // max edges per chunk staged in LDS (CE = 6250)
#define SMEMB  37376      // fused-kernel LDS bytes: part path 37376 > linear 16384

typedef __attribute__((ext_vector_type(8))) short bf16x8;
typedef __attribute__((ext_vector_type(4))) float f32x4;

__device__ __forceinline__ float leaky(float v) { return v >= 0.0f ? v : NEG_SLOPE * v; }
__device__ __forceinline__ int clampi(int v, int lo, int hi) {
    return v < lo ? lo : (v > hi ? hi : v);
}
// decode packed bf16 pair (low word / high word of a uint)
__device__ __forceinline__ float bflo(unsigned u) { return __uint_as_float(u << 16); }
__device__ __forceinline__ float bfhi(unsigned u) { return __uint_as_float(u & 0xFFFF0000u); }
// fp32 -> bf16 round-to-nearest-even
__device__ __forceinline__ unsigned short f2bf(float f) {
    unsigned u = __float_as_uint(f);
    return (unsigned short)((u + 0x7FFFu + ((u >> 16) & 1u)) >> 16);
}
__device__ __forceinline__ bf16x8 pack8(float4 a, float4 b) {
    bf16x8 r;
    r[0] = (short)f2bf(a.x); r[1] = (short)f2bf(a.y);
    r[2] = (short)f2bf(a.z); r[3] = (short)f2bf(a.w);
    r[4] = (short)f2bf(b.x); r[5] = (short)f2bf(b.y);
    r[6] = (short)f2bf(b.z); r[7] = (short)f2bf(b.w);
    return r;
}
// bijective XCD-chunked swizzle (m204): consecutive buckets land on one XCD
__device__ __forceinline__ int xcd_swz(int orig, int nwg) {
    int xcd = orig & 7;
    int i   = orig >> 3;
    int qq  = nwg >> 3, rr = nwg & 7;
    int base = (xcd < rr) ? xcd * (qq + 1) : rr * (qq + 1) + (xcd - rr) * qq;
    return base + i;
}

// K1 (fused): blocks [0, nb_lin) = MFMA linear+epilogue; blocks
// [nb_lin, nb_lin+NCHUNK) = chunk-local edge binning. Data-independent halves
// run concurrently. Round 6: the 1024-entry exclusive scan is done by wave 0
// with __shfl_up (16 vals/lane, static indices) -> 18 barriers become 2.
__global__ __launch_bounds__(512) void k_fused(
    const float* __restrict__ x, const float* __restrict__ W,
    const float* __restrict__ att_src, const float* __restrict__ att_dst,
    __hip_bfloat16* __restrict__ h, float* __restrict__ a_s,
    float* __restrict__ a_d, const int* __restrict__ ei,
    unsigned* __restrict__ binned, int* __restrict__ offc,
    int N, int E, int CE, int nb_lin)
{
    __shared__ int4 smem4[SMEMB / 16];
    const int tid = threadIdx.x;

    if ((int)blockIdx.x < nb_lin) {
        short* wlds = (short*)smem4;      // 16 frag-sets x 64 lanes x 8 bf16

        for (int idx = tid; idx < 1024; idx += 512) {
            int f = idx >> 6, L = idx & 63;
            int t = f >> 2, k0i = f & 3;
            int kbase = k0i * 32 + (L >> 4) * 8;
            int c = t * 16 + (L & 15);
            unsigned short v[8];
#pragma unroll
            for (int j = 0; j < 8; ++j) v[j] = f2bf(W[(kbase + j) * 64 + c]);
            uint4 p;
            p.x = (unsigned)v[0] | ((unsigned)v[1] << 16);
            p.y = (unsigned)v[2] | ((unsigned)v[3] << 16);
            p.z = (unsigned)v[4] | ((unsigned)v[5] << 16);
            p.w = (unsigned)v[6] | ((unsigned)v[7] << 16);
            ((uint4*)wlds)[idx] = p;
        }
        __syncthreads();

        const int lane = tid & 63;
        const int w    = tid >> 6;
        const int base = blockIdx.x * 128 + w * 16;
        const int m    = lane & 15;
        const int quad = lane >> 4;

        int rowc = min(base + m, N - 1);
        const float4* xr = (const float4*)x + (size_t)rowc * 32;

        bf16x8 afrag[4];
#pragma unroll
        for (int k0i = 0; k0i < 4; ++k0i) {
            float4 f0 = xr[k0i * 8 + quad * 2 + 0];
            float4 f1 = xr[k0i * 8 + quad * 2 + 1];
            afrag[k0i] = pack8(f0, f1);
        }

        f32x4 acc[4];
#pragma unroll
        for (int t = 0; t < 4; ++t) acc[t] = (f32x4){0.f, 0.f, 0.f, 0.f};

        const bf16x8* wf = (const bf16x8*)wlds;
#pragma unroll
        for (int t = 0; t < 4; ++t) {
#pragma unroll
            for (int k0i = 0; k0i < 4; ++k0i) {
                bf16x8 bfr = wf[(t * 4 + k0i) * 64 + lane];
                acc[t] = __builtin_amdgcn_mfma_f32_16x16x32_bf16(afrag[k0i], bfr, acc[t], 0, 0, 0);
            }
        }

        float ps[4] = {0.f, 0.f, 0.f, 0.f};
        float pd[4] = {0.f, 0.f, 0.f, 0.f};
#pragma unroll
        for (int t = 0; t < 4; ++t) {
            float as_c = att_src[t * 16 + m];
            float ad_c = att_dst[t * 16 + m];
#pragma unroll
            for (int q = 0; q < 4; ++q) {
                ps[q] = fmaf(acc[t][q], as_c, ps[q]);
                pd[q] = fmaf(acc[t][q], ad_c, pd[q]);
            }
        }
#pragma unroll
        for (int t = 0; t < 4; ++t) {
#pragma unroll
            for (int q = 0; q < 4; ++q) {
                int n = base + quad * 4 + q;
                if (n < N) h[(size_t)n * 64 + t * 16 + m] = __float2bfloat16(acc[t][q]);
            }
        }
#pragma unroll
        for (int q = 0; q < 4; ++q) {
            ps[q] += __shfl_xor(ps[q], 1, 64);
            ps[q] += __shfl_xor(ps[q], 2, 64);
            ps[q] += __shfl_xor(ps[q], 4, 64);
            ps[q] += __shfl_xor(ps[q], 8, 64);
            pd[q] += __shfl_xor(pd[q], 1, 64);
            pd[q] += __shfl_xor(pd[q], 2, 64);
            pd[q] += __shfl_xor(pd[q], 4, 64);
            pd[q] += __shfl_xor(pd[q], 8, 64);
        }
        if (m == 0) {
#pragma unroll
            for (int q = 0; q < 4; ++q) {
                int n = base + quad * 4 + q;
                if (n < N) { a_s[n] = ps[q]; a_d[n] = pd[q]; }
            }
        }
    } else {
        int* hist = (int*)smem4;              // 1024
        int* off  = hist + MAXB;              // 1024
        int* cur  = off + MAXB;               // 1024
        unsigned* stage = (unsigned*)(cur + MAXB);  // CEMAX

        const int c  = (int)blockIdx.x - nb_lin;
        const int e0 = c * CE;
        const int e1 = min(E, e0 + CE);
        const int ne = e1 - e0;

        for (int i = tid; i < MAXB; i += 512) hist[i] = 0;
        __syncthreads();
        for (int e = e0 + tid; e < e1; e += 512) {
            int dst = clampi(ei[E + e], 0, N - 1);
            atomicAdd(&hist[dst >> BSH], 1);
        }
        __syncthreads();
        // wave 0: exclusive scan of hist[0..1023] -> off, cur (no barriers)
        if (tid < 64) {
            int v[16]; int tsum = 0;
#pragma unroll
            for (int k = 0; k < 16; ++k) { v[k] = hist[tid * 16 + k]; tsum += v[k]; }
            int incl = tsum;
#pragma unroll
            for (int d = 1; d < 64; d <<= 1) {
                int t = __shfl_up(incl, d, 64);
                if (tid >= d) incl += t;
            }
            int run = incl - tsum;
#pragma unroll
            for (int k = 0; k < 16; ++k) {
                off[tid * 16 + k] = run;
                cur[tid * 16 + k] = run;
                run += v[k];
            }
        }
        __syncthreads();
        for (int e = e0 + tid; e < e1; e += 512) {
            int src = clampi(ei[e],     0, N - 1);
            int dst = clampi(ei[E + e], 0, N - 1);
            int pos = atomicAdd(&cur[dst >> BSH], 1);
            stage[clampi(pos, 0, CEMAX - 1)] =
                ((unsigned)(dst & (BNODES - 1)) << 17) | (unsigned)src;
        }
        __syncthreads();
        for (int i = tid; i < ne; i += 512) binned[e0 + i] = stage[i];
        int* oc = offc + (size_t)c * (MAXB + 1);
        for (int i = tid; i < MAXB; i += 512) oc[i] = off[i];
        if (tid == 0) oc[MAXB] = ne;
    }
}

// K2: one block (512 threads, 8 waves) per 128-node bucket.
// Round 6: Phase 0 barrier-chain removal — both scans are single-wave
// __shfl_up scans (wave 0, register-side), histogram fused into the copy
// pass; ~36 barriers -> 5. XCD-chunked bucket swizzle so adjacent buckets
// (which read adjacent offc/binned lines) share an XCD L2. Phase B is the
// round-3 depth-1 pipelined loop (depth-4 was compiler-re-serialized).
__global__ __launch_bounds__(512) void k_agg(
    const unsigned* __restrict__ binned, const int* __restrict__ offc,
    const float* __restrict__ a_s, const float* __restrict__ a_d,
    const __hip_bfloat16* __restrict__ hm, const float* __restrict__ bias,
    float* __restrict__ out, int N, int CE)
{
    __shared__ int   cnt[BNODES];
    __shared__ int   st[BNODES];
    __shared__ int   cur[BNODES];
    __shared__ float lsum[BNODES];
    __shared__ float wsl[BNODES];
    __shared__ float adl[BNODES];
    __shared__ int   runScan[NCHUNK + 1];
    __shared__ int   gbase[NCHUNK];
    __shared__ unsigned eraw[CAP];
    __shared__ uint2 ew[CAP];          // .x = src node, .y = f32 bits of w

    const int tid   = threadIdx.x;
    const int b     = xcd_swz((int)blockIdx.x, (int)gridDim.x);
    const int nbase = b << BSH;

    if (tid < BNODES) {
        cnt[tid] = 0;
        int n = nbase + tid;
        float as = 0.f, ad = 0.f;
        if (n < N) { as = a_s[n]; ad = a_d[n]; }
        adl[tid] = ad;
        float v = (n < N) ? __expf(leaky(as + ad)) : 0.f;
        wsl[tid]  = v;                 // self-loop weight
        lsum[tid] = v;                 // denominator starts with self loop
    }
    if (tid < NCHUNK) {
        const int* oc = offc + (size_t)tid * (MAXB + 1);
        int o0 = clampi(oc[b],     0, CE);
        int o1 = clampi(oc[b + 1], o0, CE);
        gbase[tid]   = tid * CE + o0;
        runScan[tid] = o1 - o0;        // run length (scanned below)
    }
    __syncthreads();                                   // B1
    // wave 0: exclusive scan of runScan[0..255] in registers
    if (tid < 64) {
        int v0 = runScan[tid * 4 + 0], v1 = runScan[tid * 4 + 1];
        int v2 = runScan[tid * 4 + 2], v3 = runScan[tid * 4 + 3];
        int tsum = v0 + v1 + v2 + v3;
        int incl = tsum;
#pragma unroll
        for (int d = 1; d < 64; d <<= 1) {
            int t = __shfl_up(incl, d, 64);
            if (tid >= d) incl += t;
        }
        int excl = incl - tsum;
        runScan[tid * 4 + 0] = excl;
        runScan[tid * 4 + 1] = excl + v0;
        runScan[tid * 4 + 2] = excl + v0 + v1;
        runScan[tid * 4 + 3] = excl + v0 + v1 + v2;
        if (tid == 63) runScan[NCHUNK] = incl;
    }
    __syncthreads();                                   // B2
    int n_e = runScan[NCHUNK];
    if (n_e > CAP) n_e = CAP;          // statistically never

    // fused: coalesced copy (binary search chunk map) + node histogram
    for (int i = tid; i < n_e; i += 512) {
        int c = 0;
#pragma unroll
        for (int stp = NCHUNK >> 1; stp >= 1; stp >>= 1)
            if (runScan[c + stp] <= i) c += stp;
        unsigned pk = binned[(size_t)gbase[c] + (i - runScan[c])];
        eraw[i] = pk;
        atomicAdd(&cnt[(pk >> 17) & (BNODES - 1)], 1);
    }
    __syncthreads();                                   // B3
    // wave 0: exclusive scan of cnt[0..127] -> st, cur
    if (tid < 64) {
        int v0 = cnt[tid * 2], v1 = cnt[tid * 2 + 1];
        int tsum = v0 + v1;
        int incl = tsum;
#pragma unroll
        for (int d = 1; d < 64; d <<= 1) {
            int t = __shfl_up(incl, d, 64);
            if (tid >= d) incl += t;
        }
        int excl = incl - tsum;
        st[tid * 2]      = excl;      cur[tid * 2]      = excl;
        st[tid * 2 + 1]  = excl + v0; cur[tid * 2 + 1]  = excl + v0;
    }
    __syncthreads();                                   // B4
    // scatter + fused attention weight + denominator (LDS -> LDS)
    for (int i = tid; i < n_e; i += 512) {
        unsigned pk = eraw[i];
        int ld  = (int)(pk >> 17) & (BNODES - 1);
        int src = (int)(pk & 0x1FFFFu);
        float wv = __expf(leaky(a_s[src] + adl[ld]));
        int pos = atomicAdd(&cur[ld], 1);
        if (pos < CAP) ew[pos] = make_uint2((unsigned)src, __float_as_uint(wv));
        atomicAdd(&lsum[ld], wv);
    }
    __syncthreads();                                   // B5

    // Phase B: lane = (node-slot p = lane>>3, octet q = lane&7)
    const int lane = tid & 63;
    const int w    = tid >> 6;       // wave 0..7
    const int q    = lane & 7;       // feature octet: features 8q..8q+7
    const int p    = lane >> 3;      // node slot 0..7
    const uint4*  h4 = (const uint4*)hm;
    const float4* b4 = (const float4*)bias;
    const float4 bb0 = b4[2 * q];
    const float4 bb1 = b4[2 * q + 1];

#pragma unroll 1
    for (int t = 0; t < 2; ++t) {
        int ln = t * 64 + w * 8 + p;
        int n  = nbase + ln;
        if (n >= N) continue;
        int deg = cnt[ln];
        int s0  = st[ln];
        if (s0 > CAP) s0 = CAP;            // defensive (never in practice)
        if (deg > CAP - s0) deg = CAP - s0;

        // self-loop contribution (each lane owns its octet exactly once)
        float wself = wsl[ln];
        uint4 U = h4[(size_t)n * 8 + q];
        float acc0 = wself * bflo(U.x), acc1 = wself * bfhi(U.x);
        float acc2 = wself * bflo(U.y), acc3 = wself * bfhi(U.y);
        float acc4 = wself * bflo(U.z), acc5 = wself * bfhi(U.z);
        float acc6 = wself * bflo(U.w), acc7 = wself * bfhi(U.w);

        float wc = 0.f;
        if (deg > 0) {
            uint2 e0 = ew[s0];
            wc = __uint_as_float(e0.y);
            U  = h4[(size_t)e0.x * 8 + q];
        }
        for (int j = 0; j < deg; ++j) {
            uint4 U2 = make_uint4(0u, 0u, 0u, 0u);
            float w2 = 0.f;
            if (j + 1 < deg) {             // prefetch next edge (depth-1)
                uint2 e1 = ew[s0 + j + 1];
                w2 = __uint_as_float(e1.y);
                U2 = h4[(size_t)e1.x * 8 + q];
            }
            acc0 = fmaf(wc, bflo(U.x), acc0);
            acc1 = fmaf(wc, bfhi(U.x), acc1);
            acc2 = fmaf(wc, bflo(U.y), acc2);
            acc3 = fmaf(wc, bfhi(U.y), acc3);
            acc4 = fmaf(wc, bflo(U.z), acc4);
            acc5 = fmaf(wc, bfhi(U.z), acc5);
            acc6 = fmaf(wc, bflo(U.w), acc6);
            acc7 = fmaf(wc, bfhi(U.w), acc7);
            U = U2; wc = w2;
        }

        float inv = 1.0f / lsum[ln];
        float4 o0, o1;
        o0.x = bb0.x + acc0 * inv;
        o0.y = bb0.y + acc1 * inv;
        o0.z = bb0.z + acc2 * inv;
        o0.w = bb0.w + acc3 * inv;
        o1.x = bb1.x + acc4 * inv;
        o1.y = bb1.y + acc5 * inv;
        o1.z = bb1.z + acc6 * inv;
        o1.w = bb1.w + acc7 * inv;
        float4* o4 = (float4*)out;
        o4[(size_t)n * 16 + 2 * q + 0] = o0;
        o4[(size_t)n * 16 + 2 * q + 1] = o1;
    }
}

extern "C" void kernel_launch(void* const* d_in, const int* in_sizes, int n_in,
                              void* d_out, int out_size, void* d_ws, size_t ws_size,
                              hipStream_t stream)
{
    const float* x       = (const float*)d_in[0];
    const int*   ei      = (const int*)d_in[1];      // int32 per harness contract
    const float* W       = (const float*)d_in[2];
    const float* att_src = (const float*)d_in[3];
    const float* att_dst = (const float*)d_in[4];
    const float* bias    = (const float*)d_in[5];
    float*       out     = (float*)d_out;

    const int N = in_sizes[0] / 128;   // 100000
    const int E = in_sizes[1] / 2;     // 1600000

    __hip_bfloat16* h      = (__hip_bfloat16*)d_ws;
    float*          a_s    = (float*)(h + (size_t)N * 64);
    float*          a_d    = a_s + N;
    int*            offc   = (int*)(a_d + N);                 // 263424 ints
    unsigned*       binned = (unsigned*)(offc + NCHUNK * (MAXB + 1));

    const int CE = (E + NCHUNK - 1) / NCHUNK;   // 6250 edges per chunk (<= CEMAX)
    const int NB = (N + BNODES - 1) >> BSH;     // 782 agg buckets
    const int nb_lin = (N + 127) / 128;         // 782 linear blocks

    k_fused<<<nb_lin + NCHUNK, 512, 0, stream>>>(x, W, att_src, att_dst,
                                                 h, a_s, a_d, ei, binned, offc,
                                                 N, E, CE, nb_lin);
    k_agg  <<<NB,              512, 0, stream>>>(binned, offc, a_s, a_d, h,
                                                 bias, out, N, CE);
}